// Round 16
// baseline (510.871 us; speedup 1.0000x reference)
//
#include <hip/hip_runtime.h>
#include <stdint.h>

constexpr int Bn = 8, Nn = 4096, Dn = 128, Cn = 256, Kn = 16;
constexpr int CH = 2048;   // KNN candidate chunk size (2 chunks of 2048)

// ---------------- Kernel A0: pack xyz -> float4 (2x, 2y, 2z, -xx) ----------------
// xx = ((x*x)+(y*y))+(z*z) with the reference rounding; 2x/2y/2z are exact (x2).
__global__ __launch_bounds__(256) void pack_kernel(const float* __restrict__ xyz, float4* __restrict__ xyzw)
{
    const int p = blockIdx.x * 256 + threadIdx.x;   // 32768 points
    const float x = xyz[p * 3 + 0], y = xyz[p * 3 + 1], z = xyz[p * 3 + 2];
    const float xx = __fadd_rn(__fadd_rn(__fmul_rn(x, x), __fmul_rn(y, y)), __fmul_rn(z, z));
    xyzw[p] = make_float4(2.0f * x, 2.0f * y, 2.0f * z, -xx);
}

// exact pd in 5 ops. Qu = (qx,qy,qz,-xxq) UNSCALED query; P = (2px,2py,2pz,-xxm) scaled candidate.
// inner2 = fma(qz,2pz, fma(qy,2py, mul_rn(qx,2px))) == 2*inner bitwise (rn(2a)=2*rn(a));
// pd = add_rn(add_rn(-xxq, inner2), -xxm) == the reference-matching formula of rounds 3-15.
__device__ __forceinline__ float pd5(const float4 Qu, const float4 P)
{
    const float inner2 = __builtin_fmaf(Qu.z, P.z, __builtin_fmaf(Qu.y, P.y, __fmul_rn(Qu.x, P.x)));
    return __fadd_rn(__fadd_rn(Qu.w, inner2), P.w);
}

// ---------------- Kernel A: exact KNN, half-sample threshold + chunked pass 2 ----------------
// 512 threads = 8 waves x 4 queries = 32 rows/block; 1024 blocks.
// __launch_bounds__(512, 2) is MANDATORY on this compiler: it is the only profile that
// yields VGPR=128 with zero spill. (512,4)/(1024,*)/no-annotation all emit the
// conservative VGPR=64 profile and spill 300-450B/thread (rounds 8,11,12,15).
// Threshold: pass 1 scans ONLY chunk 0 (32 candidates/lane). L = 16th-largest lane max.
// Validity: any subset works -- the 16 lanes with sample-max >= L each contribute one
// distinct real point >= L => |{pd >= L}| >= 16 => survivors contain the exact top-16.
// Pass 2: chunk 0 (still LDS-resident, no restage) then chunk 1; append survivor
// (value,index) via wave-private LDS atomic. Rank phase: rank-count under
// (value desc, index asc); ranks 0..15 emit == exact lax.top_k order.
// S < 16 or S > 64 (prob ~0; E[S]~32 with half-sample L) -> exhaustive rescan from GLOBAL.
__global__ __launch_bounds__(512, 2) void knn_kernel(const float4* __restrict__ xyzw, int* __restrict__ idxout)
{
    __shared__ float4 pts[CH];              // 32768 B
    __shared__ float  dv[8][4][64];         // 8192 B
    __shared__ unsigned short di[8][4][64]; // 4096 B
    __shared__ int cnt[8][4];               // 128 B
    const int tid  = threadIdx.x;
    const int wave = tid >> 6;
    const int lane = tid & 63;
    const int rbase = blockIdx.x * 32 + wave * 4;     // 32 rows/block, one batch per block
    const float4* xb = xyzw + (size_t)(rbase >> 12) * Nn;
    const int n0 = rbase & (Nn - 1);

    // queries straight from global (same bits as any staged copy)
    float4 Qu[4];
#pragma unroll
    for (int q = 0; q < 4; ++q) {
        const float4 t = xb[n0 + q];
        Qu[q] = make_float4(0.5f * t.x, 0.5f * t.y, 0.5f * t.z, t.w);   // unscale: exact
    }
    if (lane < 4) cnt[wave][lane] = 0;

    // ---- stage chunk 0 ----
#pragma unroll
    for (int t = 0; t < 4; ++t) pts[tid + t * 512] = xb[tid + t * 512];
    __syncthreads();

    // ---- pass 1 over chunk 0 only: per-lane max of exact pd (32 candidates/lane) ----
    float m0[4], m1[4];
#pragma unroll
    for (int q = 0; q < 4; ++q) { m0[q] = -3.0e38f; m1[q] = -3.0e38f; }
    for (int i = 0; i < 32; i += 2) {
        const float4 Pa = pts[(i << 6) + lane];
        const float4 Pb = pts[((i + 1) << 6) + lane];
#pragma unroll
        for (int q = 0; q < 4; ++q) {
            m0[q] = fmaxf(m0[q], pd5(Qu[q], Pa));
            m1[q] = fmaxf(m1[q], pd5(Qu[q], Pb));
        }
    }
    float s[4];
#pragma unroll
    for (int q = 0; q < 4; ++q) s[q] = fmaxf(m0[q], m1[q]);

    // ---- bitonic sort (desc) of lane maxima, 4 queries interleaved; L = rank-15 ----
#pragma unroll
    for (int k = 2; k <= 64; k <<= 1) {
#pragma unroll
        for (int j = k >> 1; j > 0; j >>= 1) {
            const bool takeMax = ((lane & j) == 0) ^ ((lane & k) != 0);
#pragma unroll
            for (int q = 0; q < 4; ++q) {
                const float o = __shfl_xor(s[q], j);
                s[q] = takeMax ? fmaxf(s[q], o) : fminf(s[q], o);
            }
        }
    }
    float L[4];
#pragma unroll
    for (int q = 0; q < 4; ++q) L[q] = __shfl(s[q], 15);

    // ---- pass 2 over chunk 0 (already resident -- no restage) ----
    for (int i = 0; i < 32; ++i) {
        const float4 P = pts[(i << 6) + lane];
        const int id = (i << 6) + lane;
#pragma unroll
        for (int q = 0; q < 4; ++q) {
            const float v = pd5(Qu[q], P);
            if (v >= L[q]) {
                const int pos = atomicAdd(&cnt[wave][q], 1);
                if (pos < 64) { dv[wave][q][pos] = v; di[wave][q][pos] = (unsigned short)id; }
            }
        }
    }

    // ---- stage chunk 1; pass 2 over it ----
    __syncthreads();   // all waves done reading chunk 0
#pragma unroll
    for (int t = 0; t < 4; ++t) pts[tid + t * 512] = xb[CH + tid + t * 512];
    __syncthreads();
    for (int i = 0; i < 32; ++i) {
        const float4 P = pts[(i << 6) + lane];
        const int id = CH + (i << 6) + lane;
#pragma unroll
        for (int q = 0; q < 4; ++q) {
            const float v = pd5(Qu[q], P);
            if (v >= L[q]) {
                const int pos = atomicAdd(&cnt[wave][q], 1);
                if (pos < 64) { dv[wave][q][pos] = v; di[wave][q][pos] = (unsigned short)id; }
            }
        }
    }

    // ---- rank-count selection + output (wave-private lists; no block barrier needed) ----
#pragma unroll
    for (int q = 0; q < 4; ++q) {
        const int S = cnt[wave][q];
        if (S >= 16 && S <= 64) {
            const float myv = dv[wave][q][lane];   // lanes >= S: garbage, writes guarded
            const int   myi = di[wave][q][lane];
            int rank = 0;
            for (int i = 0; i < S; ++i) {
                const float ov = dv[wave][q][i];   // broadcast reads
                const int   oi = di[wave][q][i];
                rank += ((ov > myv) || (ov == myv && oi < myi)) ? 1 : 0;
            }
            if (lane < S && rank < Kn) idxout[(size_t)(rbase + q) * Kn + rank] = myi;
        } else {
            // fallback: exhaustive iterative selection from GLOBAL (always correct, ~never taken)
            float prevv = 3.0e38f; int previ = -1;
            int sel = 0;
            for (int it = 0; it < Kn; ++it) {
                float bv = -3.0e38f; int bm = 0x7FFFFFFF;
                for (int i = 0; i < 64; ++i) {
                    const float4 P = xb[(i << 6) + lane];
                    const int id = (i << 6) + lane;
                    const float v = pd5(Qu[q], P);
                    const bool after = (v < prevv) || (v == prevv && id > previ);
                    if (after && (v > bv || (v == bv && id < bm))) { bv = v; bm = id; }
                }
#pragma unroll
                for (int off = 32; off; off >>= 1) {
                    const float ov = __shfl_xor(bv, off);
                    const int   om = __shfl_xor(bm, off);
                    if (ov > bv || (ov == bv && om < bm)) { bv = ov; bm = om; }
                }
                if (lane == it) sel = bm;
                prevv = bv; previ = bm;
            }
            if (lane < Kn) idxout[(size_t)(rbase + q) * Kn + lane] = sel;
        }
    }
}

// ---------------- Kernel B0: M = Wq^T @ Wk, v = bq @ Wk ----------------
__global__ __launch_bounds__(128) void prep_kernel(const float* __restrict__ Wq, const float* __restrict__ bq,
                                                   const float* __restrict__ Wk, const float* __restrict__ bk,
                                                   float* __restrict__ M, float* __restrict__ v)
{
    const int dp = blockIdx.x;   // d'
    const int d  = threadIdx.x;  // d
    float acc = 0.f;
    for (int e = 0; e < Dn; ++e) acc = fmaf(Wq[e * Dn + dp], Wk[e * Dn + d], acc);
    M[dp * Dn + d] = acc;
    if (dp == 0) {
        float a = 0.f;
        for (int e = 0; e < Dn; ++e) a = fmaf(bq[e], Wk[e * Dn + d], a);
        v[d] = a;
    }
}

// ---------------- Kernel B: t = concat @ M + v  ([32768x128] @ [128x128]) ----------------
__global__ __launch_bounds__(256) void tmat_kernel(const float* __restrict__ concat, const float* __restrict__ M,
                                                   const float* __restrict__ vvec, float* __restrict__ tout)
{
    __shared__ float As[64][33];
    __shared__ float Ms[32][128];
    const int tid = threadIdx.x;
    const int row0 = blockIdx.x * 64;
    const int tx = tid & 15;
    const int ty = tid >> 4;
    float acc[4][8];
#pragma unroll
    for (int r = 0; r < 4; ++r)
#pragma unroll
        for (int j = 0; j < 8; ++j) acc[r][j] = 0.f;

    for (int kc = 0; kc < 4; ++kc) {
        const int k0 = kc * 32;
        __syncthreads();
#pragma unroll
        for (int p = 0; p < 8; ++p) {
            const int e = p * 256 + tid;
            const int r = e >> 5, kk = e & 31;
            As[r][kk] = concat[(size_t)(row0 + r) * Dn + k0 + kk];
        }
#pragma unroll
        for (int p = 0; p < 16; ++p) {
            const int e = p * 256 + tid;
            const int kk = e >> 7, dd = e & 127;
            Ms[kk][dd] = M[(k0 + kk) * Dn + dd];
        }
        __syncthreads();
#pragma unroll
        for (int k = 0; k < 32; ++k) {
            const float4 mA = *(const float4*)(&Ms[k][tx * 8]);
            const float4 mB = *(const float4*)(&Ms[k][tx * 8 + 4]);
            const float mj[8] = {mA.x, mA.y, mA.z, mA.w, mB.x, mB.y, mB.z, mB.w};
#pragma unroll
            for (int r = 0; r < 4; ++r) {
                const float av = As[ty * 4 + r][k];
#pragma unroll
                for (int j = 0; j < 8; ++j) acc[r][j] = fmaf(av, mj[j], acc[r][j]);
            }
        }
    }
    float vv[8];
#pragma unroll
    for (int j = 0; j < 8; ++j) vv[j] = vvec[tx * 8 + j];
#pragma unroll
    for (int r = 0; r < 4; ++r)
#pragma unroll
        for (int j = 0; j < 8; ++j)
            tout[(size_t)(row0 + ty * 4 + r) * Dn + tx * 8 + j] = acc[r][j] + vv[j];
}

// ---------------- Kernel C: transpose fp4_features [B,C,N] -> featT [B,N,C] ----------------
__global__ __launch_bounds__(256) void transpose_kernel(const float* __restrict__ feat, float* __restrict__ featT)
{
    __shared__ float tile[32][33];
    const int n0 = blockIdx.x * 32;
    const int c0 = blockIdx.y * 32;
    const int b  = blockIdx.z;
    const int ln = threadIdx.x & 31, lg = threadIdx.x >> 5;
    const float* fb = feat + (size_t)b * Cn * Nn;
#pragma unroll
    for (int p = 0; p < 4; ++p) {
        const int c = lg + p * 8;
        tile[c][ln] = fb[(size_t)(c0 + c) * Nn + n0 + ln];
    }
    __syncthreads();
    float* ob = featT + (size_t)b * Nn * Cn;
#pragma unroll
    for (int p = 0; p < 4; ++p) {
        const int nn = lg + p * 8;
        ob[(size_t)(n0 + nn) * Cn + c0 + ln] = tile[ln][nn];
    }
}

// ---------------- Kernel D: fused scores + softmax + aggregation (z/s0 dropped: softmax const-shift) ----------------
__global__ __launch_bounds__(256) void fused_kernel(const float* __restrict__ concat, const float* __restrict__ tmat,
                                                    const float* __restrict__ featT, const int* __restrict__ knn,
                                                    float* __restrict__ out)
{
    __shared__ float outs[16][256];
    const int wave = threadIdx.x >> 6;
    const int lane = threadIdx.x & 63;
    const int j    = lane & 15;         // neighbor task
    const int sseg = lane >> 4;         // d-segment: d in [sseg*32, sseg*32+32)
    const int rbase = blockIdx.x * 16;
    const float scale = 0.08838834764831845f;  // 1/sqrt(128)

    for (int pt = 0; pt < 4; ++pt) {
        const int row = rbase + wave * 4 + pt;
        const int b = row >> 12;
        const int ij = knn[row * Kn + j];
        const float* trow = tmat + (size_t)row * Dn + sseg * 32;
        const float* cj   = concat + ((size_t)(b << 12) + ij) * Dn + sseg * 32;

        float pA = 0.f, pB = 0.f;
#pragma unroll
        for (int m = 0; m < 8; m += 2) {
            const float4 ta = *(const float4*)(trow + m * 4);
            const float4 ca = *(const float4*)(cj + m * 4);
            const float4 tb = *(const float4*)(trow + (m + 1) * 4);
            const float4 cb = *(const float4*)(cj + (m + 1) * 4);
            pA = fmaf(ta.x, ca.x, pA); pA = fmaf(ta.y, ca.y, pA);
            pA = fmaf(ta.z, ca.z, pA); pA = fmaf(ta.w, ca.w, pA);
            pB = fmaf(tb.x, cb.x, pB); pB = fmaf(tb.y, cb.y, pB);
            pB = fmaf(tb.z, cb.z, pB); pB = fmaf(tb.w, cb.w, pB);
        }
        float p = pA + pB;
        p += __shfl_xor(p, 16);
        p += __shfl_xor(p, 32);          // all 4 copies of task j hold t.c_j
        p *= scale;

        float mx = p;
#pragma unroll
        for (int off = 1; off <= 8; off <<= 1) mx = fmaxf(mx, __shfl_xor(mx, off));
        const float e = __expf(p - mx);
        float sum = e;
#pragma unroll
        for (int off = 1; off <= 8; off <<= 1) sum += __shfl_xor(sum, off);
        const float a = e / sum;          // this lane's neighbor-j attention

        float4 oacc = make_float4(0.f, 0.f, 0.f, 0.f);
#pragma unroll
        for (int jj = 0; jj < 16; ++jj) {
            const float aj = __shfl(a, jj);
            const int   xj = __shfl(ij, jj);
            const float4 f = *(const float4*)(&featT[((size_t)(b << 12) + xj) * Cn + lane * 4]);
            oacc.x = fmaf(aj, f.x, oacc.x);
            oacc.y = fmaf(aj, f.y, oacc.y);
            oacc.z = fmaf(aj, f.z, oacc.z);
            oacc.w = fmaf(aj, f.w, oacc.w);
        }
        *(float4*)(&outs[wave * 4 + pt][lane * 4]) = oacc;
    }
    __syncthreads();

    const int b = rbase >> 12;
    const int n0 = rbase & (Nn - 1);
#pragma unroll
    for (int p2 = 0; p2 < 16; ++p2) {
        const int c  = (threadIdx.x >> 4) + p2 * 16;
        const int nn = threadIdx.x & 15;
        out[((size_t)b * Cn + c) * Nn + n0 + nn] = outs[nn][c];
    }
}

extern "C" void kernel_launch(void* const* d_in, const int* in_sizes, int n_in,
                              void* d_out, int out_size, void* d_ws, size_t ws_size,
                              hipStream_t stream) {
    const float* xyz    = (const float*)d_in[0];   // [B,N,3]
    const float* feat   = (const float*)d_in[1];   // [B,C,N]
    const float* concat = (const float*)d_in[2];   // [B,N,D]
    const float* Wq     = (const float*)d_in[3];
    const float* bq     = (const float*)d_in[4];
    const float* Wk     = (const float*)d_in[5];
    const float* bk     = (const float*)d_in[6];
    float* out = (float*)d_out;
    float* ws  = (float*)d_ws;

    // workspace layout (float units), offsets 16B-aligned
    float*  M     = ws;                 // 16384
    float*  v     = ws + 16512;         // 128
    int*    idx   = (int*)(ws + 16704); // 32768*16 ints
    float*  t     = ws + 540992;        // 32768*128
    float*  featT = ws + 4735296;       // 8*4096*256
    float4* xyzw  = (float4*)(ws + 13123904); // 32768 float4
    // total: 13,254,976 floats = 53.0 MB

    hipLaunchKernelGGL(pack_kernel,      dim3(128),        dim3(256), 0, stream, xyz, xyzw);
    hipLaunchKernelGGL(prep_kernel,      dim3(128),        dim3(128), 0, stream, Wq, bq, Wk, bk, M, v);
    hipLaunchKernelGGL(knn_kernel,       dim3(1024),       dim3(512), 0, stream, xyzw, idx);
    hipLaunchKernelGGL(tmat_kernel,      dim3(512),        dim3(256), 0, stream, concat, M, v, t);
    hipLaunchKernelGGL(transpose_kernel, dim3(128, 8, 8),  dim3(256), 0, stream, feat, featT);
    hipLaunchKernelGGL(fused_kernel,     dim3(2048),       dim3(256), 0, stream, concat, t, featT, idx, out);
}

// Round 17
// 242.611 us; speedup vs baseline: 2.1057x; 2.1057x over previous
//
#include <hip/hip_runtime.h>
#include <stdint.h>

constexpr int Bn = 8, Nn = 4096, Dn = 128, Cn = 256, Kn = 16;

// ---------------- Kernel A0: pack xyz -> float4 (2x, 2y, 2z, -xx) ----------------
// xx = ((x*x)+(y*y))+(z*z) with the reference rounding; 2x/2y/2z are exact (x2).
__global__ __launch_bounds__(256) void pack_kernel(const float* __restrict__ xyz, float4* __restrict__ xyzw)
{
    const int p = blockIdx.x * 256 + threadIdx.x;   // 32768 points
    const float x = xyz[p * 3 + 0], y = xyz[p * 3 + 1], z = xyz[p * 3 + 2];
    const float xx = __fadd_rn(__fadd_rn(__fmul_rn(x, x), __fmul_rn(y, y)), __fmul_rn(z, z));
    xyzw[p] = make_float4(2.0f * x, 2.0f * y, 2.0f * z, -xx);
}

// exact pd in 5 ops. Qu = (qx,qy,qz,-xxq) UNSCALED query; P = (2px,2py,2pz,-xxm) scaled candidate.
// inner2 = fma(qz,2pz, fma(qy,2py, mul_rn(qx,2px))) == 2*inner bitwise (rn(2a)=2*rn(a));
// pd = add_rn(add_rn(-xxq, inner2), -xxm) == the reference-matching formula of rounds 3-16.
__device__ __forceinline__ float pd5(const float4 Qu, const float4 P)
{
    const float inner2 = __builtin_fmaf(Qu.z, P.z, __builtin_fmaf(Qu.y, P.y, __fmul_rn(Qu.x, P.x)));
    return __fadd_rn(__fadd_rn(Qu.w, inner2), P.w);
}

// ---------------- Kernel A: exact KNN, LDS-staged batch (round-13 proven version) ----------------
// 512 threads = 8 waves x 4 queries = 32 rows/block; 1024 blocks. 64KB batch staged once.
// __launch_bounds__(512,2) is the ONLY clean profile on this compiler (VGPR=128, no spill);
// (512,4)/(1024,*)/none => VGPR=64 + 300-450B/thread scratch spill (rounds 8,11,12,15).
// Pass 1 over ALL 4096 candidates: per-lane max of exact pd; L = 16th-largest lane max
// (bitonic). Full-sample L keeps E[S]~18, P(S>64)~0 -- round 16's half-sample L pushed
// the S>64 fallback rate to ~1%+ and tripled runtime. Pass 2: append survivor indices
// (ushort) via wave-private LDS atomic. Rank phase: re-derive own pd from pts (identical
// bits), rank-count via S shuffle broadcasts under (value desc, index asc); ranks 0..15
// emit == exact lax.top_k. S<16 impossible; S>64 (prob ~0) -> exhaustive LDS rescan.
__global__ __launch_bounds__(512, 2) void knn_kernel(const float4* __restrict__ xyzw, int* __restrict__ idxout)
{
    __shared__ float4 pts[Nn];              // 65536 B
    __shared__ unsigned short di[8][4][64]; // 4096 B
    __shared__ int cnt[8][4];               // 128 B
    const int tid  = threadIdx.x;
    const int wave = tid >> 6;
    const int lane = tid & 63;
    const int rbase = blockIdx.x * 32 + wave * 4;     // 32 rows/block, one batch per block
    const float4* xb = xyzw + (size_t)(rbase >> 12) * Nn;

    // ---- stage batch into LDS; init counters/lists (wave-private) ----
#pragma unroll
    for (int t = 0; t < 8; ++t) pts[tid + t * 512] = xb[tid + t * 512];
    if (lane < 4) cnt[wave][lane] = 0;
#pragma unroll
    for (int q = 0; q < 4; ++q) di[wave][q][lane] = 0;
    __syncthreads();

    const int n0 = rbase & (Nn - 1);
    float4 Qu[4];
#pragma unroll
    for (int q = 0; q < 4; ++q) {
        const float4 t = pts[n0 + q];
        Qu[q] = make_float4(0.5f * t.x, 0.5f * t.y, 0.5f * t.z, t.w);   // unscale: exact
    }

    // ---- pass 1: per-lane max of exact pd ----
    float m0[4], m1[4];
#pragma unroll
    for (int q = 0; q < 4; ++q) { m0[q] = -3.0e38f; m1[q] = -3.0e38f; }
    for (int i = 0; i < 64; i += 2) {
        const float4 Pa = pts[(i << 6) + lane];
        const float4 Pb = pts[((i + 1) << 6) + lane];
#pragma unroll
        for (int q = 0; q < 4; ++q) {
            m0[q] = fmaxf(m0[q], pd5(Qu[q], Pa));
            m1[q] = fmaxf(m1[q], pd5(Qu[q], Pb));
        }
    }
    float s[4];
#pragma unroll
    for (int q = 0; q < 4; ++q) s[q] = fmaxf(m0[q], m1[q]);

    // ---- bitonic sort (desc) of lane maxima, 4 queries interleaved; L = rank-15 ----
#pragma unroll
    for (int k = 2; k <= 64; k <<= 1) {
#pragma unroll
        for (int j = k >> 1; j > 0; j >>= 1) {
            const bool takeMax = ((lane & j) == 0) ^ ((lane & k) != 0);
#pragma unroll
            for (int q = 0; q < 4; ++q) {
                const float o = __shfl_xor(s[q], j);
                s[q] = takeMax ? fmaxf(s[q], o) : fminf(s[q], o);
            }
        }
    }
    float L[4];
#pragma unroll
    for (int q = 0; q < 4; ++q) L[q] = __shfl(s[q], 15);

    // ---- pass 2: exact pd; append survivor indices (wave-private lists, no barrier) ----
    for (int i = 0; i < 64; ++i) {
        const float4 P = pts[(i << 6) + lane];
        const int id = (i << 6) + lane;
#pragma unroll
        for (int q = 0; q < 4; ++q) {
            const float v = pd5(Qu[q], P);
            if (v >= L[q]) {
                const int pos = atomicAdd(&cnt[wave][q], 1);
                if (pos < 64) di[wave][q][pos] = (unsigned short)id;
            }
        }
    }

    // ---- rank-count selection + output ----
#pragma unroll
    for (int q = 0; q < 4; ++q) {
        const int S = cnt[wave][q];
        if (S <= 64) {   // S >= 16 guaranteed by construction
            const int   myi = di[wave][q][lane];       // lanes >= S read zero-init slots (safe)
            const float myv = pd5(Qu[q], pts[myi]);
            int rank = 0;
            for (int i = 0; i < S; ++i) {
                const float ov = __shfl(myv, i);
                const int   oi = __shfl(myi, i);
                rank += ((ov > myv) || (ov == myv && oi < myi)) ? 1 : 0;
            }
            if (lane < S && rank < Kn) idxout[(size_t)(rbase + q) * Kn + rank] = myi;
        } else {
            // fallback: exhaustive iterative selection from LDS (always correct, never expected)
            float prevv = 3.0e38f; int previ = -1;
            int sel = 0;
            for (int it = 0; it < Kn; ++it) {
                float bv = -3.0e38f; int bm = 0x7FFFFFFF;
                for (int i = 0; i < 64; ++i) {
                    const float4 P = pts[(i << 6) + lane];
                    const int id = (i << 6) + lane;
                    const float v = pd5(Qu[q], P);
                    const bool after = (v < prevv) || (v == prevv && id > previ);
                    if (after && (v > bv || (v == bv && id < bm))) { bv = v; bm = id; }
                }
#pragma unroll
                for (int off = 32; off; off >>= 1) {
                    const float ov = __shfl_xor(bv, off);
                    const int   om = __shfl_xor(bm, off);
                    if (ov > bv || (ov == bv && om < bm)) { bv = ov; bm = om; }
                }
                if (lane == it) sel = bm;
                prevv = bv; previ = bm;
            }
            if (lane < Kn) idxout[(size_t)(rbase + q) * Kn + lane] = sel;
        }
    }
}

// ---------------- Kernel B0: M = Wq^T @ Wk, v = bq @ Wk ----------------
__global__ __launch_bounds__(128) void prep_kernel(const float* __restrict__ Wq, const float* __restrict__ bq,
                                                   const float* __restrict__ Wk, const float* __restrict__ bk,
                                                   float* __restrict__ M, float* __restrict__ v)
{
    const int dp = blockIdx.x;   // d'
    const int d  = threadIdx.x;  // d
    float acc = 0.f;
    for (int e = 0; e < Dn; ++e) acc = fmaf(Wq[e * Dn + dp], Wk[e * Dn + d], acc);
    M[dp * Dn + d] = acc;
    if (dp == 0) {
        float a = 0.f;
        for (int e = 0; e < Dn; ++e) a = fmaf(bq[e], Wk[e * Dn + d], a);
        v[d] = a;
    }
}

// ---------------- Kernel B: t = concat @ M + v  ([32768x128] @ [128x128]) ----------------
__global__ __launch_bounds__(256) void tmat_kernel(const float* __restrict__ concat, const float* __restrict__ M,
                                                   const float* __restrict__ vvec, float* __restrict__ tout)
{
    __shared__ float As[64][33];
    __shared__ float Ms[32][128];
    const int tid = threadIdx.x;
    const int row0 = blockIdx.x * 64;
    const int tx = tid & 15;
    const int ty = tid >> 4;
    float acc[4][8];
#pragma unroll
    for (int r = 0; r < 4; ++r)
#pragma unroll
        for (int j = 0; j < 8; ++j) acc[r][j] = 0.f;

    for (int kc = 0; kc < 4; ++kc) {
        const int k0 = kc * 32;
        __syncthreads();
#pragma unroll
        for (int p = 0; p < 8; ++p) {
            const int e = p * 256 + tid;
            const int r = e >> 5, kk = e & 31;
            As[r][kk] = concat[(size_t)(row0 + r) * Dn + k0 + kk];
        }
#pragma unroll
        for (int p = 0; p < 16; ++p) {
            const int e = p * 256 + tid;
            const int kk = e >> 7, dd = e & 127;
            Ms[kk][dd] = M[(k0 + kk) * Dn + dd];
        }
        __syncthreads();
#pragma unroll
        for (int k = 0; k < 32; ++k) {
            const float4 mA = *(const float4*)(&Ms[k][tx * 8]);
            const float4 mB = *(const float4*)(&Ms[k][tx * 8 + 4]);
            const float mj[8] = {mA.x, mA.y, mA.z, mA.w, mB.x, mB.y, mB.z, mB.w};
#pragma unroll
            for (int r = 0; r < 4; ++r) {
                const float av = As[ty * 4 + r][k];
#pragma unroll
                for (int j = 0; j < 8; ++j) acc[r][j] = fmaf(av, mj[j], acc[r][j]);
            }
        }
    }
    float vv[8];
#pragma unroll
    for (int j = 0; j < 8; ++j) vv[j] = vvec[tx * 8 + j];
#pragma unroll
    for (int r = 0; r < 4; ++r)
#pragma unroll
        for (int j = 0; j < 8; ++j)
            tout[(size_t)(row0 + ty * 4 + r) * Dn + tx * 8 + j] = acc[r][j] + vv[j];
}

// ---------------- Kernel C: transpose fp4_features [B,C,N] -> featT [B,N,C] ----------------
__global__ __launch_bounds__(256) void transpose_kernel(const float* __restrict__ feat, float* __restrict__ featT)
{
    __shared__ float tile[32][33];
    const int n0 = blockIdx.x * 32;
    const int c0 = blockIdx.y * 32;
    const int b  = blockIdx.z;
    const int ln = threadIdx.x & 31, lg = threadIdx.x >> 5;
    const float* fb = feat + (size_t)b * Cn * Nn;
#pragma unroll
    for (int p = 0; p < 4; ++p) {
        const int c = lg + p * 8;
        tile[c][ln] = fb[(size_t)(c0 + c) * Nn + n0 + ln];
    }
    __syncthreads();
    float* ob = featT + (size_t)b * Nn * Cn;
#pragma unroll
    for (int p = 0; p < 4; ++p) {
        const int nn = lg + p * 8;
        ob[(size_t)(n0 + nn) * Cn + c0 + ln] = tile[ln][nn];
    }
}

// ---------------- Kernel D: fused scores + softmax + aggregation, XCD-chunked swizzle ----------------
// Gathers ~24KB of random rows per query (16x512B concat + 16x1KB featT) from the query's
// batch. Default round-robin block->XCD placement mixes all 8 batches into every XCD's
// 4MB L2 (32MB working set -> L3 gathers). Chunked swizzle (HW assigns dispatch id d to
// XCD d%8): swz=(bid&7)*256+(bid>>3) gives XCD k exactly batch k -- featT[k] (4MB) fits
// its L2 exactly. Bijective since 2048%8==0. Softmax math unchanged (z/s0 const-shift).
__global__ __launch_bounds__(256) void fused_kernel(const float* __restrict__ concat, const float* __restrict__ tmat,
                                                    const float* __restrict__ featT, const int* __restrict__ knn,
                                                    float* __restrict__ out)
{
    __shared__ float outs[16][256];
    const int wave = threadIdx.x >> 6;
    const int lane = threadIdx.x & 63;
    const int j    = lane & 15;         // neighbor task
    const int sseg = lane >> 4;         // d-segment: d in [sseg*32, sseg*32+32)
    const int swz  = (blockIdx.x & 7) * 256 + (blockIdx.x >> 3);   // XCD-chunked remap
    const int rbase = swz * 16;
    const float scale = 0.08838834764831845f;  // 1/sqrt(128)

    for (int pt = 0; pt < 4; ++pt) {
        const int row = rbase + wave * 4 + pt;
        const int b = row >> 12;
        const int ij = knn[row * Kn + j];
        const float* trow = tmat + (size_t)row * Dn + sseg * 32;
        const float* cj   = concat + ((size_t)(b << 12) + ij) * Dn + sseg * 32;

        float pA = 0.f, pB = 0.f;
#pragma unroll
        for (int m = 0; m < 8; m += 2) {
            const float4 ta = *(const float4*)(trow + m * 4);
            const float4 ca = *(const float4*)(cj + m * 4);
            const float4 tb = *(const float4*)(trow + (m + 1) * 4);
            const float4 cb = *(const float4*)(cj + (m + 1) * 4);
            pA = fmaf(ta.x, ca.x, pA); pA = fmaf(ta.y, ca.y, pA);
            pA = fmaf(ta.z, ca.z, pA); pA = fmaf(ta.w, ca.w, pA);
            pB = fmaf(tb.x, cb.x, pB); pB = fmaf(tb.y, cb.y, pB);
            pB = fmaf(tb.z, cb.z, pB); pB = fmaf(tb.w, cb.w, pB);
        }
        float p = pA + pB;
        p += __shfl_xor(p, 16);
        p += __shfl_xor(p, 32);          // all 4 copies of task j hold t.c_j
        p *= scale;

        float mx = p;
#pragma unroll
        for (int off = 1; off <= 8; off <<= 1) mx = fmaxf(mx, __shfl_xor(mx, off));
        const float e = __expf(p - mx);
        float sum = e;
#pragma unroll
        for (int off = 1; off <= 8; off <<= 1) sum += __shfl_xor(sum, off);
        const float a = e / sum;          // this lane's neighbor-j attention

        float4 oacc = make_float4(0.f, 0.f, 0.f, 0.f);
#pragma unroll
        for (int jj = 0; jj < 16; ++jj) {
            const float aj = __shfl(a, jj);
            const int   xj = __shfl(ij, jj);
            const float4 f = *(const float4*)(&featT[((size_t)(b << 12) + xj) * Cn + lane * 4]);
            oacc.x = fmaf(aj, f.x, oacc.x);
            oacc.y = fmaf(aj, f.y, oacc.y);
            oacc.z = fmaf(aj, f.z, oacc.z);
            oacc.w = fmaf(aj, f.w, oacc.w);
        }
        *(float4*)(&outs[wave * 4 + pt][lane * 4]) = oacc;
    }
    __syncthreads();

    const int b = rbase >> 12;
    const int n0 = rbase & (Nn - 1);
#pragma unroll
    for (int p2 = 0; p2 < 16; ++p2) {
        const int c  = (threadIdx.x >> 4) + p2 * 16;
        const int nn = threadIdx.x & 15;
        out[((size_t)b * Cn + c) * Nn + n0 + nn] = outs[nn][c];
    }
}

extern "C" void kernel_launch(void* const* d_in, const int* in_sizes, int n_in,
                              void* d_out, int out_size, void* d_ws, size_t ws_size,
                              hipStream_t stream) {
    const float* xyz    = (const float*)d_in[0];   // [B,N,3]
    const float* feat   = (const float*)d_in[1];   // [B,C,N]
    const float* concat = (const float*)d_in[2];   // [B,N,D]
    const float* Wq     = (const float*)d_in[3];
    const float* bq     = (const float*)d_in[4];
    const float* Wk     = (const float*)d_in[5];
    const float* bk     = (const float*)d_in[6];
    float* out = (float*)d_out;
    float* ws  = (float*)d_ws;

    // workspace layout (float units), offsets 16B-aligned
    float*  M     = ws;                 // 16384
    float*  v     = ws + 16512;         // 128
    int*    idx   = (int*)(ws + 16704); // 32768*16 ints
    float*  t     = ws + 540992;        // 32768*128
    float*  featT = ws + 4735296;       // 8*4096*256
    float4* xyzw  = (float4*)(ws + 13123904); // 32768 float4
    // total: 13,254,976 floats = 53.0 MB

    hipLaunchKernelGGL(pack_kernel,      dim3(128),        dim3(256), 0, stream, xyz, xyzw);
    hipLaunchKernelGGL(prep_kernel,      dim3(128),        dim3(128), 0, stream, Wq, bq, Wk, bk, M, v);
    hipLaunchKernelGGL(knn_kernel,       dim3(1024),       dim3(512), 0, stream, xyzw, idx);
    hipLaunchKernelGGL(tmat_kernel,      dim3(512),        dim3(256), 0, stream, concat, M, v, t);
    hipLaunchKernelGGL(transpose_kernel, dim3(128, 8, 8),  dim3(256), 0, stream, feat, featT);
    hipLaunchKernelGGL(fused_kernel,     dim3(2048),       dim3(256), 0, stream, concat, t, featT, idx, out);
}